// Round 18
// baseline (88.767 us; speedup 1.0000x reference)
//
#include <hip/hip_runtime.h>
#include <stdint.h>

// Batched kNN (k=20, D=3) vs fp32 numpy/XLA-CPU reference. Numerics LOCKED
// (R4 passed absmax=0):
//   sq  = ((x0*x0 + x1*x1) + x2*x2)          plain chain
//   dot = fmaf(x2,y2, fmaf(x1,y1, x0*y0))    FMA ascending-k
//   d   = (sqi+sqj) - 2f*dot == fmaf(-2f, dot, sqi+sqj)   (2*dot exact)
// fp32 ties re-ranked by exact fp64 distance, then ORIGINAL index.
//
// R18 = R17 + two final trims:
//  1. __launch_bounds__(256, 4) on main: VGPR cap 128 (was ~85) at the SAME
//     measured occupancy (4 waves/SIMD) -> all 28 dwordx4 loads in flight.
//  2. bounds_kernel folded into scatter: each block binary-searches batch
//     for its cloud's [lb(c), lb(c+1)) (serial, hidden across 56 blocks);
//     block (c,0) publishes starts[c]. One launch + one full scan removed.

#define MAXC 28            // candidates/lane
#define PADC 1792          // MAXC*64; cloud capacity (actual ~1536 +- 37)
#define NCLOUDS 8
#define ROWS_PER_BLOCK 4   // 1 row per wave, 256-thread blocks
#define BIGF 3.0e38f

__device__ __forceinline__ unsigned int map32(float d) {
    unsigned int u = __float_as_uint(d);
    return u ^ (unsigned int)(((int)u >> 31) | 0x80000000);
}

__device__ __forceinline__ unsigned long long map64(double d) {
    unsigned long long u = __double_as_longlong(d);
    return u ^ (unsigned long long)(((long long)u >> 63) |
                                    (long long)0x8000000000000000ull);
}

__device__ __forceinline__ unsigned int umin2(unsigned int a, unsigned int b) {
    return a < b ? a : b;
}

// Full-wave unsigned-min via DPP (fallback path only).
__device__ __forceinline__ unsigned int wave_umin_dpp(unsigned int v) {
    int x = (int)v, t;
    t = __builtin_amdgcn_update_dpp(-1, x, 0x111, 0xf, 0xf, false);
    x = (int)umin2((unsigned int)x, (unsigned int)t);
    t = __builtin_amdgcn_update_dpp(-1, x, 0x112, 0xf, 0xf, false);
    x = (int)umin2((unsigned int)x, (unsigned int)t);
    t = __builtin_amdgcn_update_dpp(-1, x, 0x114, 0xf, 0xf, false);
    x = (int)umin2((unsigned int)x, (unsigned int)t);
    t = __builtin_amdgcn_update_dpp(-1, x, 0x118, 0xf, 0xf, false);
    x = (int)umin2((unsigned int)x, (unsigned int)t);
    t = __builtin_amdgcn_update_dpp(-1, x, 0x142, 0xa, 0xf, false);
    x = (int)umin2((unsigned int)x, (unsigned int)t);
    t = __builtin_amdgcn_update_dpp(-1, x, 0x143, 0xc, 0xf, false);
    x = (int)umin2((unsigned int)x, (unsigned int)t);
    return (unsigned int)__builtin_amdgcn_readlane(x, 63);
}

// Serial lower_bound over sorted batch[0..n): first idx with batch[idx] >= key.
__device__ __forceinline__ int lb_serial(const int* __restrict__ batch,
                                         int n, int key) {
    int lo = 0, hi = n;
    while (lo < hi) {
        int mid = (lo + hi) >> 1;      // in [0, n)
        if (batch[mid] < key) lo = mid + 1;
        else hi = mid;
    }
    return lo;
}

__global__ void scatter_kernel(const float* __restrict__ x,
                               const int* __restrict__ batch, int n,
                               int* __restrict__ starts,
                               float4* __restrict__ pts) {
#pragma clang fp contract(off)
    __shared__ int sb[2];
    const int c = blockIdx.x / (PADC / 256);       // 7 blocks per cloud
    const int rbase = (blockIdx.x % (PADC / 256)) * 256;
    if (threadIdx.x == 0) {
        sb[0] = lb_serial(batch, n, c);
        sb[1] = lb_serial(batch, n, c + 1);
        if (rbase == 0) starts[c] = sb[0];         // publish for main kernel
    }
    __syncthreads();
    const int s = sb[0], e = sb[1];

    const int r = rbase + threadIdx.x;
    const int p = c * PADC + r;
    const int j = s + r;
    if (j < e) {
        float x0 = x[3 * j + 0];
        float x1 = x[3 * j + 1];
        float x2 = x[3 * j + 2];
        float sq = x0 * x0 + x1 * x1 + x2 * x2;  // LOCKED plain chain
        pts[p] = make_float4(x0, x1, x2, sq);
    } else {
        pts[p] = make_float4(1e18f, 1e18f, 1e18f, 3e36f);  // finite-huge
    }
}

__global__ __launch_bounds__(256, 4) void knn_main_kernel(
        const float4* __restrict__ pts,
        const int* __restrict__ batch,
        const int* __restrict__ starts,
        int k, int n,
        int* __restrict__ out) {
#pragma clang fp contract(off)
    __shared__ int coll[ROWS_PER_BLOCK][64];
    __shared__ int lcnt[ROWS_PER_BLOCK];
    const int wave = threadIdx.x >> 6;
    const int lane = threadIdx.x & 63;
    const int i = blockIdx.x * ROWS_PER_BLOCK + wave;  // one row per wave
    if (i >= n) return;

    const int b = batch[i];
    const int s0 = starts[b];            // valid: b appears in batch
    const int cbase = b * PADC;
    const float4 q = pts[cbase + (i - s0)];  // (x,y,z,sq) of row i

    // Build float keys: 1 dwordx4 + 6 VALU per candidate, no bounds logic.
    float slots[MAXC];
    float c0 = BIGF, c1 = BIGF, c2 = BIGF, c3 = BIGF;
#pragma unroll
    for (int t = 0; t < MAXC; ++t) {
        const float4 wj = pts[cbase + lane + t * 64];
        float dot = __builtin_fmaf(q.z, wj.z,
                    __builtin_fmaf(q.y, wj.y, q.x * wj.x));
        float s = q.w + wj.w;
        float d = __builtin_fmaf(-2.0f, dot, s);  // == s - 2f*dot exactly
        slots[t] = d;
        switch (t & 3) {
            case 0: c0 = fminf(c0, d); break;
            case 1: c1 = fminf(c1, d); break;
            case 2: c2 = fminf(c2, d); break;
            default: c3 = fminf(c3, d); break;
        }
    }
    const float localmin = fminf(fminf(c0, c1), fminf(c2, c3));

    // Bitonic sort of 64 lane-mins; T = k-th smallest (upper bound on the
    // k-th smallest candidate). Floats finite, no NaN, no -0.
    float v = localmin;
#pragma unroll
    for (int kk = 2; kk <= 64; kk <<= 1) {
#pragma unroll
        for (int jj = kk >> 1; jj > 0; jj >>= 1) {
            float p = __int_as_float(__shfl_xor(__float_as_int(v), jj));
            bool keepMin = (((lane & jj) == 0) == ((lane & kk) == 0));
            v = keepMin ? fminf(v, p) : fmaxf(v, p);
        }
    }
    const float T = __int_as_float(
        __builtin_amdgcn_readlane(__float_as_int(v), k - 1));

    // Phase 2: hitmask + per-wave LDS-atomic compaction (unordered; P3
    // exact-ranks the set). DS ops are wave-ordered: init -> adds -> read.
    unsigned int hm = 0;
#pragma unroll
    for (int t = 0; t < MAXC; ++t)
        hm |= (slots[t] <= T) ? (1u << t) : 0u;  // sentinels never hit

    if (lane == 0) lcnt[wave] = 0;
    unsigned int m = hm;
    while (m) {
        int t = __builtin_ctz(m);
        m &= m - 1;
        int off = atomicAdd(&lcnt[wave], 1);
        if (off < 64) coll[wave][off] = lane + t * 64;
    }
    int cnt = atomicAdd(&lcnt[wave], 0);  // wave-ordered read

    if (cnt > 64) {
        // Fallback (wave-uniform, astronomically rare): exact u32
        // threshold-ascent for the k-th distinct value, then recompact.
        unsigned int thrp1 = 0, Tu = 0;
        for (int r = 0; r < k; ++r) {
            unsigned int m0 = map32(slots[0]) - thrp1;
#pragma unroll
            for (int t = 1; t < MAXC; ++t)
                m0 = umin2(m0, map32(slots[t]) - thrp1);
            Tu = wave_umin_dpp(m0) + thrp1;
            thrp1 = Tu + 1;
        }
        int base = 0;
#pragma unroll
        for (int t = 0; t < MAXC; ++t) {
            bool hit = (map32(slots[t]) <= Tu);
            unsigned long long bal = __ballot(hit);
            int off = base + __builtin_amdgcn_mbcnt_hi(
                                 (unsigned int)(bal >> 32),
                                 __builtin_amdgcn_mbcnt_lo((unsigned int)bal, 0));
            if (hit && off < 64) coll[wave][off] = lane + t * 64;
            base += (int)__popcll(bal);
        }
        cnt = base;
    }
    if (cnt > 64) cnt = 64;  // wave-uniform

    // Phase 3, common path: rank collected candidates by fp32 d alone,
    // counting exact-equal values in the same loop.
    const bool valid = (lane < cnt);
    const int slot = valid ? coll[wave][lane] : 0;
    float v32 = BIGF;
    int oidx = 0;
    if (valid) {
        const float4 wj = pts[cbase + slot];
        oidx = s0 + slot;
        float dot = __builtin_fmaf(q.z, wj.z,
                    __builtin_fmaf(q.y, wj.y, q.x * wj.x));
        float s = q.w + wj.w;
        v32 = __builtin_fmaf(-2.0f, dot, s);  // bit-identical to build
    }

    int pos = 0, eq = 0;
    for (int s = 0; s < cnt; ++s) {
        float vs = __int_as_float(__shfl(__float_as_int(v32), s));
        pos += (vs < v32) ? 1 : 0;
        eq += (vs == v32) ? 1 : 0;
    }

    // Rare path: duplicate fp32 values among valid lanes -> resolve with the
    // exact (fp32, fp64, idx) 3-key loop (LOCKED semantics).
    if (__ballot(valid && eq > 1)) {
        unsigned long long m64 = ~0ull;
        if (valid) {
            const float4 wj = pts[cbase + slot];
            // exact fp64 (products of fp32 are exact in double)
            double q0 = (double)q.x * (double)q.x;
            double q1 = (double)q.y * (double)q.y;
            double q2 = (double)q.z * (double)q.z;
            double sqdi = (q0 + q1) + q2;
            double w0 = (double)wj.x * (double)wj.x;
            double w1 = (double)wj.y * (double)wj.y;
            double w2 = (double)wj.z * (double)wj.z;
            double sqdj = (w0 + w1) + w2;
            double p0 = (double)q.x * (double)wj.x;
            double p1 = (double)q.y * (double)wj.y;
            double p2 = (double)q.z * (double)wj.z;
            double dot64 = (p0 + p1) + p2;
            double d64 = (sqdi + sqdj) - 2.0 * dot64;
            m64 = map64(d64);
        }
        pos = 0;
        for (int s = 0; s < cnt; ++s) {
            float vs = __int_as_float(__shfl(__float_as_int(v32), s));
            unsigned long long ms = __shfl(m64, s);
            int is_ = __shfl(oidx, s);
            bool less = (vs < v32) ||
                        (vs == v32 && (ms < m64 || (ms == m64 && is_ < oidx)));
            pos += less ? 1 : 0;
        }
    }

    if (valid && pos < k) out[(long long)i * k + pos] = oidx;
}

extern "C" void kernel_launch(void* const* d_in, const int* in_sizes, int n_in,
                              void* d_out, int out_size, void* d_ws, size_t ws_size,
                              hipStream_t stream) {
    const float* x = (const float*)d_in[0];
    const int* batch = (const int*)d_in[1];
    const int n = in_sizes[1];            // 12288 points
    const int k = out_size / n;           // 20
    int* out = (int*)d_out;

    char* ws = (char*)d_ws;
    float4* pts = (float4*)ws;            ws += (size_t)NCLOUDS * PADC * sizeof(float4);
    int* starts = (int*)ws;

    scatter_kernel<<<NCLOUDS * (PADC / 256), 256, 0, stream>>>(x, batch, n, starts, pts);
    const int blocks = (n + ROWS_PER_BLOCK - 1) / ROWS_PER_BLOCK;  // 3072
    knn_main_kernel<<<blocks, 256, 0, stream>>>(pts, batch, starts, k, n, out);
}

// Round 19
// 81.479 us; speedup vs baseline: 1.0894x; 1.0894x over previous
//
#include <hip/hip_runtime.h>
#include <stdint.h>

// Batched kNN (k=20, D=3) vs fp32 numpy/XLA-CPU reference. Numerics LOCKED
// (R4 passed absmax=0):
//   sq  = ((x0*x0 + x1*x1) + x2*x2)          plain chain
//   dot = fmaf(x2,y2, fmaf(x1,y1, x0*y0))    FMA ascending-k
//   d   = (sqi+sqj) - 2f*dot == fmaf(-2f, dot, sqi+sqj)   (2*dot exact)
// fp32 ties re-ranked by exact fp64 distance, then ORIGINAL index.
//
// R19 = R18 with launch_bounds REVERTED to (256, 6).
//  R18 post-mortem: (256,4) let the allocator spend up to 128 VGPR and
//  dropped guaranteed occupancy 24 -> 16 waves/CU on a latency-bound kernel
//  (-8.7 us). (256,6) = 6 waves/SIMD guaranteed at ~85 VGPR cap — the R17
//  sweet spot. Folded scatter (binary-search bounds, 1 launch saved) kept
//  as the single remaining R18 delta under test.

#define MAXC 28            // candidates/lane
#define PADC 1792          // MAXC*64; cloud capacity (actual ~1536 +- 37)
#define NCLOUDS 8
#define ROWS_PER_BLOCK 4   // 1 row per wave, 256-thread blocks
#define BIGF 3.0e38f

__device__ __forceinline__ unsigned int map32(float d) {
    unsigned int u = __float_as_uint(d);
    return u ^ (unsigned int)(((int)u >> 31) | 0x80000000);
}

__device__ __forceinline__ unsigned long long map64(double d) {
    unsigned long long u = __double_as_longlong(d);
    return u ^ (unsigned long long)(((long long)u >> 63) |
                                    (long long)0x8000000000000000ull);
}

__device__ __forceinline__ unsigned int umin2(unsigned int a, unsigned int b) {
    return a < b ? a : b;
}

// Full-wave unsigned-min via DPP (fallback path only).
__device__ __forceinline__ unsigned int wave_umin_dpp(unsigned int v) {
    int x = (int)v, t;
    t = __builtin_amdgcn_update_dpp(-1, x, 0x111, 0xf, 0xf, false);
    x = (int)umin2((unsigned int)x, (unsigned int)t);
    t = __builtin_amdgcn_update_dpp(-1, x, 0x112, 0xf, 0xf, false);
    x = (int)umin2((unsigned int)x, (unsigned int)t);
    t = __builtin_amdgcn_update_dpp(-1, x, 0x114, 0xf, 0xf, false);
    x = (int)umin2((unsigned int)x, (unsigned int)t);
    t = __builtin_amdgcn_update_dpp(-1, x, 0x118, 0xf, 0xf, false);
    x = (int)umin2((unsigned int)x, (unsigned int)t);
    t = __builtin_amdgcn_update_dpp(-1, x, 0x142, 0xa, 0xf, false);
    x = (int)umin2((unsigned int)x, (unsigned int)t);
    t = __builtin_amdgcn_update_dpp(-1, x, 0x143, 0xc, 0xf, false);
    x = (int)umin2((unsigned int)x, (unsigned int)t);
    return (unsigned int)__builtin_amdgcn_readlane(x, 63);
}

// Serial lower_bound over sorted batch[0..n): first idx with batch[idx] >= key.
__device__ __forceinline__ int lb_serial(const int* __restrict__ batch,
                                         int n, int key) {
    int lo = 0, hi = n;
    while (lo < hi) {
        int mid = (lo + hi) >> 1;      // in [0, n)
        if (batch[mid] < key) lo = mid + 1;
        else hi = mid;
    }
    return lo;
}

__global__ void scatter_kernel(const float* __restrict__ x,
                               const int* __restrict__ batch, int n,
                               int* __restrict__ starts,
                               float4* __restrict__ pts) {
#pragma clang fp contract(off)
    __shared__ int sb[2];
    const int c = blockIdx.x / (PADC / 256);       // 7 blocks per cloud
    const int rbase = (blockIdx.x % (PADC / 256)) * 256;
    if (threadIdx.x == 0) {
        sb[0] = lb_serial(batch, n, c);
        sb[1] = lb_serial(batch, n, c + 1);
        if (rbase == 0) starts[c] = sb[0];         // publish for main kernel
    }
    __syncthreads();
    const int s = sb[0], e = sb[1];

    const int r = rbase + threadIdx.x;
    const int p = c * PADC + r;
    const int j = s + r;
    if (j < e) {
        float x0 = x[3 * j + 0];
        float x1 = x[3 * j + 1];
        float x2 = x[3 * j + 2];
        float sq = x0 * x0 + x1 * x1 + x2 * x2;  // LOCKED plain chain
        pts[p] = make_float4(x0, x1, x2, sq);
    } else {
        pts[p] = make_float4(1e18f, 1e18f, 1e18f, 3e36f);  // finite-huge
    }
}

__global__ __launch_bounds__(256, 6) void knn_main_kernel(
        const float4* __restrict__ pts,
        const int* __restrict__ batch,
        const int* __restrict__ starts,
        int k, int n,
        int* __restrict__ out) {
#pragma clang fp contract(off)
    __shared__ int coll[ROWS_PER_BLOCK][64];
    __shared__ int lcnt[ROWS_PER_BLOCK];
    const int wave = threadIdx.x >> 6;
    const int lane = threadIdx.x & 63;
    const int i = blockIdx.x * ROWS_PER_BLOCK + wave;  // one row per wave
    if (i >= n) return;

    const int b = batch[i];
    const int s0 = starts[b];            // valid: b appears in batch
    const int cbase = b * PADC;
    const float4 q = pts[cbase + (i - s0)];  // (x,y,z,sq) of row i

    // Build float keys: 1 dwordx4 + 6 VALU per candidate, no bounds logic.
    float slots[MAXC];
    float c0 = BIGF, c1 = BIGF, c2 = BIGF, c3 = BIGF;
#pragma unroll
    for (int t = 0; t < MAXC; ++t) {
        const float4 wj = pts[cbase + lane + t * 64];
        float dot = __builtin_fmaf(q.z, wj.z,
                    __builtin_fmaf(q.y, wj.y, q.x * wj.x));
        float s = q.w + wj.w;
        float d = __builtin_fmaf(-2.0f, dot, s);  // == s - 2f*dot exactly
        slots[t] = d;
        switch (t & 3) {
            case 0: c0 = fminf(c0, d); break;
            case 1: c1 = fminf(c1, d); break;
            case 2: c2 = fminf(c2, d); break;
            default: c3 = fminf(c3, d); break;
        }
    }
    const float localmin = fminf(fminf(c0, c1), fminf(c2, c3));

    // Bitonic sort of 64 lane-mins; T = k-th smallest (upper bound on the
    // k-th smallest candidate). Floats finite, no NaN, no -0.
    float v = localmin;
#pragma unroll
    for (int kk = 2; kk <= 64; kk <<= 1) {
#pragma unroll
        for (int jj = kk >> 1; jj > 0; jj >>= 1) {
            float p = __int_as_float(__shfl_xor(__float_as_int(v), jj));
            bool keepMin = (((lane & jj) == 0) == ((lane & kk) == 0));
            v = keepMin ? fminf(v, p) : fmaxf(v, p);
        }
    }
    const float T = __int_as_float(
        __builtin_amdgcn_readlane(__float_as_int(v), k - 1));

    // Phase 2: hitmask + per-wave LDS-atomic compaction (unordered; P3
    // exact-ranks the set). DS ops are wave-ordered: init -> adds -> read.
    unsigned int hm = 0;
#pragma unroll
    for (int t = 0; t < MAXC; ++t)
        hm |= (slots[t] <= T) ? (1u << t) : 0u;  // sentinels never hit

    if (lane == 0) lcnt[wave] = 0;
    unsigned int m = hm;
    while (m) {
        int t = __builtin_ctz(m);
        m &= m - 1;
        int off = atomicAdd(&lcnt[wave], 1);
        if (off < 64) coll[wave][off] = lane + t * 64;
    }
    int cnt = atomicAdd(&lcnt[wave], 0);  // wave-ordered read

    if (cnt > 64) {
        // Fallback (wave-uniform, astronomically rare): exact u32
        // threshold-ascent for the k-th distinct value, then recompact.
        unsigned int thrp1 = 0, Tu = 0;
        for (int r = 0; r < k; ++r) {
            unsigned int m0 = map32(slots[0]) - thrp1;
#pragma unroll
            for (int t = 1; t < MAXC; ++t)
                m0 = umin2(m0, map32(slots[t]) - thrp1);
            Tu = wave_umin_dpp(m0) + thrp1;
            thrp1 = Tu + 1;
        }
        int base = 0;
#pragma unroll
        for (int t = 0; t < MAXC; ++t) {
            bool hit = (map32(slots[t]) <= Tu);
            unsigned long long bal = __ballot(hit);
            int off = base + __builtin_amdgcn_mbcnt_hi(
                                 (unsigned int)(bal >> 32),
                                 __builtin_amdgcn_mbcnt_lo((unsigned int)bal, 0));
            if (hit && off < 64) coll[wave][off] = lane + t * 64;
            base += (int)__popcll(bal);
        }
        cnt = base;
    }
    if (cnt > 64) cnt = 64;  // wave-uniform

    // Phase 3, common path: rank collected candidates by fp32 d alone,
    // counting exact-equal values in the same loop.
    const bool valid = (lane < cnt);
    const int slot = valid ? coll[wave][lane] : 0;
    float v32 = BIGF;
    int oidx = 0;
    if (valid) {
        const float4 wj = pts[cbase + slot];
        oidx = s0 + slot;
        float dot = __builtin_fmaf(q.z, wj.z,
                    __builtin_fmaf(q.y, wj.y, q.x * wj.x));
        float s = q.w + wj.w;
        v32 = __builtin_fmaf(-2.0f, dot, s);  // bit-identical to build
    }

    int pos = 0, eq = 0;
    for (int s = 0; s < cnt; ++s) {
        float vs = __int_as_float(__shfl(__float_as_int(v32), s));
        pos += (vs < v32) ? 1 : 0;
        eq += (vs == v32) ? 1 : 0;
    }

    // Rare path: duplicate fp32 values among valid lanes -> resolve with the
    // exact (fp32, fp64, idx) 3-key loop (LOCKED semantics).
    if (__ballot(valid && eq > 1)) {
        unsigned long long m64 = ~0ull;
        if (valid) {
            const float4 wj = pts[cbase + slot];
            // exact fp64 (products of fp32 are exact in double)
            double q0 = (double)q.x * (double)q.x;
            double q1 = (double)q.y * (double)q.y;
            double q2 = (double)q.z * (double)q.z;
            double sqdi = (q0 + q1) + q2;
            double w0 = (double)wj.x * (double)wj.x;
            double w1 = (double)wj.y * (double)wj.y;
            double w2 = (double)wj.z * (double)wj.z;
            double sqdj = (w0 + w1) + w2;
            double p0 = (double)q.x * (double)wj.x;
            double p1 = (double)q.y * (double)wj.y;
            double p2 = (double)q.z * (double)wj.z;
            double dot64 = (p0 + p1) + p2;
            double d64 = (sqdi + sqdj) - 2.0 * dot64;
            m64 = map64(d64);
        }
        pos = 0;
        for (int s = 0; s < cnt; ++s) {
            float vs = __int_as_float(__shfl(__float_as_int(v32), s));
            unsigned long long ms = __shfl(m64, s);
            int is_ = __shfl(oidx, s);
            bool less = (vs < v32) ||
                        (vs == v32 && (ms < m64 || (ms == m64 && is_ < oidx)));
            pos += less ? 1 : 0;
        }
    }

    if (valid && pos < k) out[(long long)i * k + pos] = oidx;
}

extern "C" void kernel_launch(void* const* d_in, const int* in_sizes, int n_in,
                              void* d_out, int out_size, void* d_ws, size_t ws_size,
                              hipStream_t stream) {
    const float* x = (const float*)d_in[0];
    const int* batch = (const int*)d_in[1];
    const int n = in_sizes[1];            // 12288 points
    const int k = out_size / n;           // 20
    int* out = (int*)d_out;

    char* ws = (char*)d_ws;
    float4* pts = (float4*)ws;            ws += (size_t)NCLOUDS * PADC * sizeof(float4);
    int* starts = (int*)ws;

    scatter_kernel<<<NCLOUDS * (PADC / 256), 256, 0, stream>>>(x, batch, n, starts, pts);
    const int blocks = (n + ROWS_PER_BLOCK - 1) / ROWS_PER_BLOCK;  // 3072
    knn_main_kernel<<<blocks, 256, 0, stream>>>(pts, batch, starts, k, n, out);
}

// Round 20
// 79.043 us; speedup vs baseline: 1.1230x; 1.0308x over previous
//
#include <hip/hip_runtime.h>
#include <stdint.h>

// Batched kNN (k=20, D=3) vs fp32 numpy/XLA-CPU reference. Numerics LOCKED
// (R4 passed absmax=0):
//   sq  = ((x0*x0 + x1*x1) + x2*x2)          plain chain
//   dot = fmaf(x2,y2, fmaf(x1,y1, x0*y0))    FMA ascending-k
//   d   = (sqi+sqj) - 2f*dot == fmaf(-2f, dot, sqi+sqj)   (2*dot exact)
// fp32 ties re-ranked by exact fp64 distance, then ORIGINAL index.
//
// R20 = exact R17 restore (best measured: 80.1 us total).
//  - bounds_kernel (separate launch) + sentinel-guarded scatter: R19 showed
//    the folded binary-search scatter is ~neutral-to-negative.
//  - main kernel: R17 config — 1 row/wave, 28 register float slots,
//    __launch_bounds__(256,6) (R18 proved (256,4) loses 8.7 us via
//    occupancy), bitonic-T, hitmask+LDS-atomic compaction, two-phase P3.
// Ceiling accounting: ~50 us structural harness floor (256 MiB ws re-poison
// fill at ~6.6 TB/s = 40 us, memory-bound, + ~10 us launch/graph) +
// ~4 us prep + ~26 us latency-bound main whose structural alternatives
// (R9/R12/R13/R18) all regressed.

#define MAXC 28            // candidates/lane
#define PADC 1792          // MAXC*64; cloud capacity (actual ~1536 +- 37)
#define NCLOUDS 8
#define ROWS_PER_BLOCK 4   // 1 row per wave, 256-thread blocks
#define BIGF 3.0e38f

__device__ __forceinline__ unsigned int map32(float d) {
    unsigned int u = __float_as_uint(d);
    return u ^ (unsigned int)(((int)u >> 31) | 0x80000000);
}

__device__ __forceinline__ unsigned long long map64(double d) {
    unsigned long long u = __double_as_longlong(d);
    return u ^ (unsigned long long)(((long long)u >> 63) |
                                    (long long)0x8000000000000000ull);
}

__device__ __forceinline__ unsigned int umin2(unsigned int a, unsigned int b) {
    return a < b ? a : b;
}

// Full-wave unsigned-min via DPP (fallback path only).
__device__ __forceinline__ unsigned int wave_umin_dpp(unsigned int v) {
    int x = (int)v, t;
    t = __builtin_amdgcn_update_dpp(-1, x, 0x111, 0xf, 0xf, false);
    x = (int)umin2((unsigned int)x, (unsigned int)t);
    t = __builtin_amdgcn_update_dpp(-1, x, 0x112, 0xf, 0xf, false);
    x = (int)umin2((unsigned int)x, (unsigned int)t);
    t = __builtin_amdgcn_update_dpp(-1, x, 0x114, 0xf, 0xf, false);
    x = (int)umin2((unsigned int)x, (unsigned int)t);
    t = __builtin_amdgcn_update_dpp(-1, x, 0x118, 0xf, 0xf, false);
    x = (int)umin2((unsigned int)x, (unsigned int)t);
    t = __builtin_amdgcn_update_dpp(-1, x, 0x142, 0xa, 0xf, false);
    x = (int)umin2((unsigned int)x, (unsigned int)t);
    t = __builtin_amdgcn_update_dpp(-1, x, 0x143, 0xc, 0xf, false);
    x = (int)umin2((unsigned int)x, (unsigned int)t);
    return (unsigned int)__builtin_amdgcn_readlane(x, 63);
}

__global__ void bounds_kernel(const int* __restrict__ batch, int n,
                              int* __restrict__ starts, int* __restrict__ ends) {
    int j = blockIdx.x * blockDim.x + threadIdx.x;
    if (j >= n) return;
    int b = batch[j];
    if (b < 0 || b >= NCLOUDS) return;  // safety
    if (j == 0 || batch[j - 1] != b) starts[b] = j;
    if (j == n - 1 || batch[j + 1] != b) ends[b] = j + 1;
}

__global__ void scatter_kernel(const float* __restrict__ x, int n,
                               const int* __restrict__ starts,
                               const int* __restrict__ ends,
                               float4* __restrict__ pts) {
#pragma clang fp contract(off)
    int p = blockIdx.x * blockDim.x + threadIdx.x;
    if (p >= NCLOUDS * PADC) return;
    int c = p / PADC;
    int r = p - c * PADC;
    int s = starts[c];
    int e = ends[c];
    // Poison-guard (cloud absent from batch -> starts/ends stay 0xAA...).
    bool ok = (s >= 0) && (e <= n) && (s < e);
    int j = s + r;
    if (ok && j < e) {
        float x0 = x[3 * j + 0];
        float x1 = x[3 * j + 1];
        float x2 = x[3 * j + 2];
        float sq = x0 * x0 + x1 * x1 + x2 * x2;  // LOCKED plain chain
        pts[p] = make_float4(x0, x1, x2, sq);
    } else {
        pts[p] = make_float4(1e18f, 1e18f, 1e18f, 3e36f);  // finite-huge
    }
}

__global__ __launch_bounds__(256, 6) void knn_main_kernel(
        const float4* __restrict__ pts,
        const int* __restrict__ batch,
        const int* __restrict__ starts,
        int k, int n,
        int* __restrict__ out) {
#pragma clang fp contract(off)
    __shared__ int coll[ROWS_PER_BLOCK][64];
    __shared__ int lcnt[ROWS_PER_BLOCK];
    const int wave = threadIdx.x >> 6;
    const int lane = threadIdx.x & 63;
    const int i = blockIdx.x * ROWS_PER_BLOCK + wave;  // one row per wave
    if (i >= n) return;

    const int b = batch[i];
    const int s0 = starts[b];            // valid: b appears in batch
    const int cbase = b * PADC;
    const float4 q = pts[cbase + (i - s0)];  // (x,y,z,sq) of row i

    // Build float keys: 1 dwordx4 + 6 VALU per candidate, no bounds logic.
    float slots[MAXC];
    float c0 = BIGF, c1 = BIGF, c2 = BIGF, c3 = BIGF;
#pragma unroll
    for (int t = 0; t < MAXC; ++t) {
        const float4 wj = pts[cbase + lane + t * 64];
        float dot = __builtin_fmaf(q.z, wj.z,
                    __builtin_fmaf(q.y, wj.y, q.x * wj.x));
        float s = q.w + wj.w;
        float d = __builtin_fmaf(-2.0f, dot, s);  // == s - 2f*dot exactly
        slots[t] = d;
        switch (t & 3) {
            case 0: c0 = fminf(c0, d); break;
            case 1: c1 = fminf(c1, d); break;
            case 2: c2 = fminf(c2, d); break;
            default: c3 = fminf(c3, d); break;
        }
    }
    const float localmin = fminf(fminf(c0, c1), fminf(c2, c3));

    // Bitonic sort of 64 lane-mins; T = k-th smallest (upper bound on the
    // k-th smallest candidate). Floats finite, no NaN, no -0.
    float v = localmin;
#pragma unroll
    for (int kk = 2; kk <= 64; kk <<= 1) {
#pragma unroll
        for (int jj = kk >> 1; jj > 0; jj >>= 1) {
            float p = __int_as_float(__shfl_xor(__float_as_int(v), jj));
            bool keepMin = (((lane & jj) == 0) == ((lane & kk) == 0));
            v = keepMin ? fminf(v, p) : fmaxf(v, p);
        }
    }
    const float T = __int_as_float(
        __builtin_amdgcn_readlane(__float_as_int(v), k - 1));

    // Phase 2: hitmask + per-wave LDS-atomic compaction (unordered; P3
    // exact-ranks the set). DS ops are wave-ordered: init -> adds -> read.
    unsigned int hm = 0;
#pragma unroll
    for (int t = 0; t < MAXC; ++t)
        hm |= (slots[t] <= T) ? (1u << t) : 0u;  // sentinels never hit

    if (lane == 0) lcnt[wave] = 0;
    unsigned int m = hm;
    while (m) {
        int t = __builtin_ctz(m);
        m &= m - 1;
        int off = atomicAdd(&lcnt[wave], 1);
        if (off < 64) coll[wave][off] = lane + t * 64;
    }
    int cnt = atomicAdd(&lcnt[wave], 0);  // wave-ordered read

    if (cnt > 64) {
        // Fallback (wave-uniform, astronomically rare): exact u32
        // threshold-ascent for the k-th distinct value, then recompact.
        unsigned int thrp1 = 0, Tu = 0;
        for (int r = 0; r < k; ++r) {
            unsigned int m0 = map32(slots[0]) - thrp1;
#pragma unroll
            for (int t = 1; t < MAXC; ++t)
                m0 = umin2(m0, map32(slots[t]) - thrp1);
            Tu = wave_umin_dpp(m0) + thrp1;
            thrp1 = Tu + 1;
        }
        int base = 0;
#pragma unroll
        for (int t = 0; t < MAXC; ++t) {
            bool hit = (map32(slots[t]) <= Tu);
            unsigned long long bal = __ballot(hit);
            int off = base + __builtin_amdgcn_mbcnt_hi(
                                 (unsigned int)(bal >> 32),
                                 __builtin_amdgcn_mbcnt_lo((unsigned int)bal, 0));
            if (hit && off < 64) coll[wave][off] = lane + t * 64;
            base += (int)__popcll(bal);
        }
        cnt = base;
    }
    if (cnt > 64) cnt = 64;  // wave-uniform

    // Phase 3, common path: rank collected candidates by fp32 d alone,
    // counting exact-equal values in the same loop.
    const bool valid = (lane < cnt);
    const int slot = valid ? coll[wave][lane] : 0;
    float v32 = BIGF;
    int oidx = 0;
    if (valid) {
        const float4 wj = pts[cbase + slot];
        oidx = s0 + slot;
        float dot = __builtin_fmaf(q.z, wj.z,
                    __builtin_fmaf(q.y, wj.y, q.x * wj.x));
        float s = q.w + wj.w;
        v32 = __builtin_fmaf(-2.0f, dot, s);  // bit-identical to build
    }

    int pos = 0, eq = 0;
    for (int s = 0; s < cnt; ++s) {
        float vs = __int_as_float(__shfl(__float_as_int(v32), s));
        pos += (vs < v32) ? 1 : 0;
        eq += (vs == v32) ? 1 : 0;
    }

    // Rare path: duplicate fp32 values among valid lanes -> resolve with the
    // exact (fp32, fp64, idx) 3-key loop (LOCKED semantics).
    if (__ballot(valid && eq > 1)) {
        unsigned long long m64 = ~0ull;
        if (valid) {
            const float4 wj = pts[cbase + slot];
            // exact fp64 (products of fp32 are exact in double)
            double q0 = (double)q.x * (double)q.x;
            double q1 = (double)q.y * (double)q.y;
            double q2 = (double)q.z * (double)q.z;
            double sqdi = (q0 + q1) + q2;
            double w0 = (double)wj.x * (double)wj.x;
            double w1 = (double)wj.y * (double)wj.y;
            double w2 = (double)wj.z * (double)wj.z;
            double sqdj = (w0 + w1) + w2;
            double p0 = (double)q.x * (double)wj.x;
            double p1 = (double)q.y * (double)wj.y;
            double p2 = (double)q.z * (double)wj.z;
            double dot64 = (p0 + p1) + p2;
            double d64 = (sqdi + sqdj) - 2.0 * dot64;
            m64 = map64(d64);
        }
        pos = 0;
        for (int s = 0; s < cnt; ++s) {
            float vs = __int_as_float(__shfl(__float_as_int(v32), s));
            unsigned long long ms = __shfl(m64, s);
            int is_ = __shfl(oidx, s);
            bool less = (vs < v32) ||
                        (vs == v32 && (ms < m64 || (ms == m64 && is_ < oidx)));
            pos += less ? 1 : 0;
        }
    }

    if (valid && pos < k) out[(long long)i * k + pos] = oidx;
}

extern "C" void kernel_launch(void* const* d_in, const int* in_sizes, int n_in,
                              void* d_out, int out_size, void* d_ws, size_t ws_size,
                              hipStream_t stream) {
    const float* x = (const float*)d_in[0];
    const int* batch = (const int*)d_in[1];
    const int n = in_sizes[1];            // 12288 points
    const int k = out_size / n;           // 20
    int* out = (int*)d_out;

    char* ws = (char*)d_ws;
    float4* pts = (float4*)ws;            ws += (size_t)NCLOUDS * PADC * sizeof(float4);
    int* starts = (int*)ws;               ws += NCLOUDS * sizeof(int);
    int* ends = (int*)ws;

    bounds_kernel<<<(n + 255) / 256, 256, 0, stream>>>(batch, n, starts, ends);
    scatter_kernel<<<(NCLOUDS * PADC + 255) / 256, 256, 0, stream>>>(x, n, starts, ends, pts);
    const int blocks = (n + ROWS_PER_BLOCK - 1) / ROWS_PER_BLOCK;  // 3072
    knn_main_kernel<<<blocks, 256, 0, stream>>>(pts, batch, starts, k, n, out);
}